// Round 1
// baseline (886.373 us; speedup 1.0000x reference)
//
#include <hip/hip_runtime.h>

// B=2, H=16, S=2048, D=64, fp32 in/out; out = [ctx | attn] concatenated.
#define S_LEN  2048
#define DH     64
#define NHEAD  16
#define NBATCH 2
#define SCALE  0.125f
#define NEG_BIG (-1e9f)

typedef short bf16x8 __attribute__((ext_vector_type(8)));
typedef float f32x4  __attribute__((ext_vector_type(4)));

static __device__ __forceinline__ short f2b(float f) {
  return __builtin_bit_cast(short, (__bf16)f);
}
static __device__ __forceinline__ bf16x8 pack8(float4 a, float4 b) {
  bf16x8 r;
  r[0] = f2b(a.x); r[1] = f2b(a.y); r[2] = f2b(a.z); r[3] = f2b(a.w);
  r[4] = f2b(b.x); r[5] = f2b(b.y); r[6] = f2b(b.z); r[7] = f2b(b.w);
  return r;
}
static __device__ __forceinline__ unsigned int packbf2(float lo, float hi) {
  unsigned short l = __builtin_bit_cast(unsigned short, (__bf16)lo);
  unsigned short h = __builtin_bit_cast(unsigned short, (__bf16)hi);
  return ((unsigned int)h << 16) | (unsigned int)l;
}

// 256 threads = 4 waves. Pass 1: BARRIER-FREE column-split — each wave computes
// denominator partials for ALL 64 q-rows over its own 512-col strip, loading K
// B-frags straight from global (L2-resident). One LDS reduce at the end.
// Pass 2: wave w owns q-rows [16w,16w+16); K/V staged in LDS with async
// register prefetch (issue next tile's loads before compute of current tile).
__global__ __launch_bounds__(256, 4)
void sdpa_mfma(const float* __restrict__ Qg, const float* __restrict__ Kg,
               const float* __restrict__ Vg, const int* __restrict__ Mg,
               float* __restrict__ ctx_g, float* __restrict__ attn_g) {
  // K tile as bf16 [kcol][d], 16B-chunk XOR-swizzled (chunk ^= row&7)
  __shared__ __align__(16) short Kb[64 * 64];
  // V tile transposed bf16 [d][k], same chunk swizzle
  __shared__ __align__(16) short Vt[64 * 64];
  // P tile fp32 [q][k], stride 68 (272B = 16B-aligned rows)
  __shared__ __align__(16) float Ps[64 * 68];
  // pass-1 denominator partials: [wave][row]
  __shared__ float Lred[4 * 64];

  const int tid  = threadIdx.x;
  const int w    = tid >> 6;     // wave id 0..3
  const int lane = tid & 63;
  const int l15  = lane & 15;
  const int quad = lane >> 4;
  const int q0 = blockIdx.x * 64;
  const int h  = blockIdx.y;
  const int b  = blockIdx.z;

  const size_t head = (size_t)(b * NHEAD + h);
  const float* Qh = Qg + head * S_LEN * DH;
  const float* Kh = Kg + head * S_LEN * DH;
  const float* Vh = Vg + head * S_LEN * DH;
  const int*   Mb = Mg + (size_t)b * S_LEN * S_LEN;
  float* ctxh  = ctx_g  + head * S_LEN * DH;
  float* attnh = attn_g + head * S_LEN * S_LEN;

  // ---- Q A-frags for ALL 4 row-groups (A[m=l15][k=8*quad+j], two K=32 steps) ----
  bf16x8 aqA[4], aqB[4];   // indexed only with compile-time constants
  #pragma unroll
  for (int rg = 0; rg < 4; ++rg) {
    const float* qp = Qh + (size_t)(q0 + 16 * rg + l15) * DH + (quad << 3);
    float4 f0 = ((const float4*)qp)[0];
    float4 f1 = ((const float4*)qp)[1];
    float4 f2 = ((const float4*)qp)[8];
    float4 f3 = ((const float4*)qp)[9];
    aqA[rg] = pack8(f0, f1);
    aqB[rg] = pack8(f2, f3);
  }

  // ================= pass 1: denominators, barrier-free column strips =========
  // wave w covers columns [512w, 512w+512); 8 iterations of 64 columns.
  float lsum[16] = {0.f};  // [rg*4 + reg]
  {
    const int* mb1 = Mb + (size_t)(q0 + 4 * quad) * S_LEN + l15;
    const int kw = w << 9;  // w*512
    for (int it = 0; it < 8; ++it) {
      const int k0 = kw + (it << 6);
      #pragma unroll
      for (int jt = 0; jt < 4; ++jt) {
        // direct global->B-frag: B[n=l15][k=8*quad+j], rows k0+16jt+l15
        const float* kp = Kh + (size_t)(k0 + (jt << 4) + l15) * DH + (quad << 3);
        float4 f0 = ((const float4*)kp)[0];
        float4 f1 = ((const float4*)kp)[1];
        float4 f2 = ((const float4*)kp)[8];
        float4 f3 = ((const float4*)kp)[9];
        bf16x8 b0 = pack8(f0, f1);
        bf16x8 b1 = pack8(f2, f3);

        int mv[16];
        #pragma unroll
        for (int i = 0; i < 16; ++i)  // i = rg*4+reg
          mv[i] = mb1[(16 * (i >> 2) + (i & 3)) * S_LEN + k0 + (jt << 4)];

        #pragma unroll
        for (int rg = 0; rg < 4; ++rg) {
          f32x4 acc = {0.f, 0.f, 0.f, 0.f};
          acc = __builtin_amdgcn_mfma_f32_16x16x32_bf16(aqA[rg], b0, acc, 0, 0, 0);
          acc = __builtin_amdgcn_mfma_f32_16x16x32_bf16(aqB[rg], b1, acc, 0, 0, 0);
          #pragma unroll
          for (int reg = 0; reg < 4; ++reg) {
            float s = mv[rg * 4 + reg] ? NEG_BIG : acc[reg] * SCALE;
            lsum[rg * 4 + reg] += __expf(s);
          }
        }
      }
    }
  }

  // reduce over l15 lanes, publish per-wave partials
  #pragma unroll
  for (int i = 0; i < 16; ++i) {
    float t = lsum[i];
    t += __shfl_xor(t, 1);
    t += __shfl_xor(t, 2);
    t += __shfl_xor(t, 4);
    t += __shfl_xor(t, 8);
    if (l15 == 0) Lred[(w << 6) + 16 * (i >> 2) + 4 * quad + (i & 3)] = t;
  }
  __syncthreads();

  // ---- pass-2 staging indices + first tile prefetch (issue before LDS reads) ----
  const int srow = tid >> 2, sseg = tid & 3;       // K staging
  const int vp = tid >> 3, vcb = (tid & 7) << 3;   // V staging
  float4 pkA, pkB, pkC, pkD, pva, pvb, pvc, pvd;
  #define LOADK(K0) do { \
    const float* kp_ = Kh + (size_t)((K0) + srow) * DH + (sseg << 4); \
    pkA = ((const float4*)kp_)[0]; pkB = ((const float4*)kp_)[1]; \
    pkC = ((const float4*)kp_)[2]; pkD = ((const float4*)kp_)[3]; } while (0)
  #define LOADV(K0) do { \
    const float* v0_ = Vh + (size_t)((K0) + 2 * vp) * DH + vcb; \
    pva = ((const float4*)v0_)[0]; pvb = ((const float4*)v0_)[1]; \
    pvc = ((const float4*)(v0_ + DH))[0]; pvd = ((const float4*)(v0_ + DH))[1]; } while (0)
  LOADK(0);
  LOADV(0);

  // combine 4 wave partials -> 1/denominator for this wave's own rows
  float invl[4];
  #pragma unroll
  for (int reg = 0; reg < 4; ++reg) {
    int r = 16 * w + 4 * quad + reg;
    invl[reg] = 1.0f / (Lred[r] + Lred[64 + r] + Lred[128 + r] + Lred[192 + r]);
  }

  // wave's own Q A-frags (wave-uniform branch; keeps array indices static)
  bf16x8 aq0, aq1;
  if      (w == 0) { aq0 = aqA[0]; aq1 = aqB[0]; }
  else if (w == 1) { aq0 = aqA[1]; aq1 = aqB[1]; }
  else if (w == 2) { aq0 = aqA[2]; aq1 = aqB[2]; }
  else             { aq0 = aqA[3]; aq1 = aqB[3]; }

  f32x4 cacc[4];
  #pragma unroll
  for (int jt = 0; jt < 4; ++jt) cacc[jt] = (f32x4){0.f, 0.f, 0.f, 0.f};

  const int* mb2 = Mb + (size_t)(q0 + 16 * w + 4 * quad) * S_LEN + l15;
  float* ab = attnh + (size_t)(q0 + 16 * w + 4 * quad) * S_LEN + l15;

  // ====================== pass 2: attn write + P·V MFMA ======================
  for (int k0 = 0; k0 < S_LEN; k0 += 64) {
    __syncthreads();   // prior compute done reading Kb/Vt
    {
      int base = srow << 6, x = srow & 7;
      *(bf16x8*)&Kb[base + ((((sseg << 1)    ) ^ x) << 3)] = pack8(pkA, pkB);
      *(bf16x8*)&Kb[base + ((((sseg << 1) | 1) ^ x) << 3)] = pack8(pkC, pkD);

      float lo[8] = {pva.x, pva.y, pva.z, pva.w, pvb.x, pvb.y, pvb.z, pvb.w};
      float hi[8] = {pvc.x, pvc.y, pvc.z, pvc.w, pvd.x, pvd.y, pvd.z, pvd.w};
      int ch = vp >> 2, wi = (vp & 3) << 1;
      #pragma unroll
      for (int c = 0; c < 8; ++c) {
        int dd = vcb + c;
        *(unsigned int*)&Vt[(dd << 6) + ((ch ^ (dd & 7)) << 3) + wi] =
            packbf2(lo[c], hi[c]);
      }
    }
    __syncthreads();
    // async prefetch of next tile: loads fly while we compute this tile
    if (k0 + 64 < S_LEN) { LOADK(k0 + 64); LOADV(k0 + 64); }

    int mv[16];
    #pragma unroll
    for (int i = 0; i < 16; ++i)   // i = reg*4 + jt
      mv[i] = mb2[(i >> 2) * S_LEN + k0 + ((i & 3) << 4)];

    f32x4 sc[4];
    __builtin_amdgcn_s_setprio(1);
    #pragma unroll
    for (int jt = 0; jt < 4; ++jt) {
      int row = (jt << 4) + l15, x = l15 & 7;
      bf16x8 b0 = *(const bf16x8*)&Kb[(row << 6) + (((quad    ) ^ x) << 3)];
      bf16x8 b1 = *(const bf16x8*)&Kb[(row << 6) + (((quad | 4) ^ x) << 3)];
      f32x4 acc = {0.f, 0.f, 0.f, 0.f};
      acc = __builtin_amdgcn_mfma_f32_16x16x32_bf16(aq0, b0, acc, 0, 0, 0);
      acc = __builtin_amdgcn_mfma_f32_16x16x32_bf16(aq1, b1, acc, 0, 0, 0);
      sc[jt] = acc;
    }
    __builtin_amdgcn_s_setprio(0);

    #pragma unroll
    for (int reg = 0; reg < 4; ++reg) {
      float* prow = &Ps[(16 * w + 4 * quad + reg) * 68 + l15];
      #pragma unroll
      for (int jt = 0; jt < 4; ++jt) {
        float s = mv[reg * 4 + jt] ? NEG_BIG : sc[jt][reg] * SCALE;
        float p = __expf(s) * invl[reg];
        // write-once stream: nontemporal keeps K/V/mask resident in L2/LLC
        __builtin_nontemporal_store(p, &ab[(reg * S_LEN) + k0 + (jt << 4)]);
        prow[jt << 4] = p;               // LDS, 2-way banks (free)
      }
    }

    // P A-frags: wave reads only its own 16 rows (written by this wave above;
    // per-wave in-order LDS => no barrier needed)
    bf16x8 ap0, ap1;
    {
      const float* pp = &Ps[(16 * w + l15) * 68 + (quad << 3)];
      float4 p0 = ((const float4*)pp)[0];
      float4 p1 = ((const float4*)pp)[1];
      float4 p2 = ((const float4*)pp)[8];
      float4 p3 = ((const float4*)pp)[9];
      ap0 = pack8(p0, p1);
      ap1 = pack8(p2, p3);
    }
    __builtin_amdgcn_s_setprio(1);
    #pragma unroll
    for (int jt = 0; jt < 4; ++jt) {
      int d = (jt << 4) + l15, x = l15 & 7;
      bf16x8 bv0 = *(const bf16x8*)&Vt[(d << 6) + (((quad    ) ^ x) << 3)];
      bf16x8 bv1 = *(const bf16x8*)&Vt[(d << 6) + (((quad | 4) ^ x) << 3)];
      cacc[jt] = __builtin_amdgcn_mfma_f32_16x16x32_bf16(ap0, bv0, cacc[jt], 0, 0, 0);
      cacc[jt] = __builtin_amdgcn_mfma_f32_16x16x32_bf16(ap1, bv1, cacc[jt], 0, 0, 0);
    }
    __builtin_amdgcn_s_setprio(0);
  }

  // ---- ctx epilogue ----
  #pragma unroll
  for (int reg = 0; reg < 4; ++reg) {
    float* crow = ctxh + (size_t)(q0 + 16 * w + 4 * quad + reg) * DH + l15;
    #pragma unroll
    for (int jt = 0; jt < 4; ++jt)
      __builtin_nontemporal_store(cacc[jt][reg], &crow[jt << 4]);
  }
}

extern "C" void kernel_launch(void* const* d_in, const int* in_sizes, int n_in,
                              void* d_out, int out_size, void* d_ws, size_t ws_size,
                              hipStream_t stream) {
  (void)in_sizes; (void)n_in; (void)d_ws; (void)ws_size; (void)out_size;
  const float* Q = (const float*)d_in[0];
  const float* K = (const float*)d_in[1];
  const float* V = (const float*)d_in[2];
  const int*   M = (const int*)d_in[3];
  float* ctx  = (float*)d_out;
  float* attn = ctx + (size_t)NBATCH * NHEAD * S_LEN * DH;
  dim3 grid(S_LEN / 64, NHEAD, NBATCH);
  sdpa_mfma<<<grid, dim3(256), 0, stream>>>(Q, K, V, M, ctx, attn);
}

// Round 2
// 774.171 us; speedup vs baseline: 1.1449x; 1.1449x over previous
//
#include <hip/hip_runtime.h>

// B=2, H=16, S=2048, D=64, fp32 in/out; out = [ctx | attn] concatenated.
#define S_LEN  2048
#define DH     64
#define NHEAD  16
#define NBATCH 2
#define SCALE  0.125f
#define L2E_SC 0.18033688011112042f   /* SCALE * log2(e) */
#define NEG_BIG (-1e9f)

typedef short bf16x8 __attribute__((ext_vector_type(8)));
typedef float f32x4  __attribute__((ext_vector_type(4)));

static __device__ __forceinline__ short f2b(float f) {
  return __builtin_bit_cast(short, (__bf16)f);
}
static __device__ __forceinline__ bf16x8 pack8(float4 a, float4 b) {
  bf16x8 r;
  r[0] = f2b(a.x); r[1] = f2b(a.y); r[2] = f2b(a.z); r[3] = f2b(a.w);
  r[4] = f2b(b.x); r[5] = f2b(b.y); r[6] = f2b(b.z); r[7] = f2b(b.w);
  return r;
}
static __device__ __forceinline__ unsigned int packbf2(float lo, float hi) {
  unsigned short l = __builtin_bit_cast(unsigned short, (__bf16)lo);
  unsigned short h = __builtin_bit_cast(unsigned short, (__bf16)hi);
  return ((unsigned int)h << 16) | (unsigned int)l;
}

// 256 threads = 4 waves; wave w owns q-rows [16w,16w+16) of a 64-row tile.
// Two passes over K: (1) softmax denom only, (2) recompute -> attn + P·V.
// T14 async-STAGE: global loads for tile i+1 are issued right after the
// staging barrier of tile i, so HBM/LLC latency hides under compute.
__global__ __launch_bounds__(256, 3)
void sdpa_mfma(const float* __restrict__ Qg, const float* __restrict__ Kg,
               const float* __restrict__ Vg, const int* __restrict__ Mg,
               float* __restrict__ ctx_g, float* __restrict__ attn_g) {
  // K tile as bf16 [kcol][d], 16B-chunk XOR-swizzled (chunk ^= row&7)
  __shared__ __align__(16) short Kb[64 * 64];
  // V tile transposed bf16 [d][k], same chunk swizzle
  __shared__ __align__(16) short Vt[64 * 64];
  // P tile fp32 [q][k], stride 68 (272B = 16B-aligned rows)
  __shared__ __align__(16) float Ps[64 * 68];

  const int tid  = threadIdx.x;
  const int w    = tid >> 6;     // wave id 0..3
  const int lane = tid & 63;
  const int l15  = lane & 15;
  const int quad = lane >> 4;
  const int q0 = blockIdx.x * 64;
  const int h  = blockIdx.y;
  const int b  = blockIdx.z;

  const size_t head = (size_t)(b * NHEAD + h);
  const float* Qh = Qg + head * S_LEN * DH;
  const float* Kh = Kg + head * S_LEN * DH;
  const float* Vh = Vg + head * S_LEN * DH;
  const int*   Mb = Mg + (size_t)b * S_LEN * S_LEN;
  float* ctxh  = ctx_g  + head * S_LEN * DH;
  float* attnh = attn_g + head * S_LEN * S_LEN;
  // attn row addr = mask row addr + constant byte delta (both 4B elems, same
  // row layout) -> saves 8 VGPRs of pointer state
  const ptrdiff_t dAM = (const char*)attnh - (const char*)Mb;

  // ---- persistent Q A-fragments (A[m=l15][k=8*quad+j], two K=32 steps) ----
  bf16x8 aq0, aq1;
  {
    const float* qp = Qh + (size_t)(q0 + 16 * w + l15) * DH + (quad << 3);
    aq0 = pack8(((const float4*)qp)[0], ((const float4*)qp)[1]);
    aq1 = pack8(((const float4*)qp)[8], ((const float4*)qp)[9]);
  }

  // mask row base pointers (C-layout rows: 4*quad+reg within wave slab)
  const int* mrow[4];
  #pragma unroll
  for (int reg = 0; reg < 4; ++reg) {
    int grow = q0 + 16 * w + 4 * quad + reg;
    mrow[reg] = Mb + (size_t)grow * S_LEN + l15;
  }

  // staging index precompute
  const int srow = tid >> 2, sseg = tid & 3;       // K staging
  const int vp = tid >> 3, vcb = (tid & 7) << 3;   // V staging

  // ---- prefetch registers ----
  float4 pkA, pkB, pkC, pkD, pva, pvb, pvc, pvd;
  int mvc[16];  // mask values for the CURRENT tile, i = reg*4 + jt

#define LOADK(K0) do { \
    const float* kp_ = Kh + (size_t)((K0) + srow) * DH + (sseg << 4); \
    pkA = ((const float4*)kp_)[0]; pkB = ((const float4*)kp_)[1]; \
    pkC = ((const float4*)kp_)[2]; pkD = ((const float4*)kp_)[3]; } while (0)
#define LOADV(K0) do { \
    const float* v0_ = Vh + (size_t)((K0) + 2 * vp) * DH + vcb; \
    pva = ((const float4*)v0_)[0]; pvb = ((const float4*)v0_)[1]; \
    pvc = ((const float4*)(v0_ + DH))[0]; pvd = ((const float4*)(v0_ + DH))[1]; } while (0)
#define LOADM(K0) do { \
    mvc[0]  = mrow[0][(K0)];      mvc[1]  = mrow[0][(K0) + 16]; \
    mvc[2]  = mrow[0][(K0) + 32]; mvc[3]  = mrow[0][(K0) + 48]; \
    mvc[4]  = mrow[1][(K0)];      mvc[5]  = mrow[1][(K0) + 16]; \
    mvc[6]  = mrow[1][(K0) + 32]; mvc[7]  = mrow[1][(K0) + 48]; \
    mvc[8]  = mrow[2][(K0)];      mvc[9]  = mrow[2][(K0) + 16]; \
    mvc[10] = mrow[2][(K0) + 32]; mvc[11] = mrow[2][(K0) + 48]; \
    mvc[12] = mrow[3][(K0)];      mvc[13] = mrow[3][(K0) + 16]; \
    mvc[14] = mrow[3][(K0) + 32]; mvc[15] = mrow[3][(K0) + 48]; } while (0)
#define STOREK() do { \
    int base_ = srow << 6, x_ = srow & 7; \
    *(bf16x8*)&Kb[base_ + ((((sseg << 1)    ) ^ x_) << 3)] = pack8(pkA, pkB); \
    *(bf16x8*)&Kb[base_ + ((((sseg << 1) | 1) ^ x_) << 3)] = pack8(pkC, pkD); } while (0)

  float lsum[4] = {0.f, 0.f, 0.f, 0.f};
  LOADK(0);
  LOADM(0);

  // =========================== pass 1: denominators ===========================
  for (int k0 = 0; k0 < S_LEN; k0 += 64) {
    __syncthreads();          // prior compute done reading Kb
    STOREK();
    __syncthreads();
    if (k0 + 64 < S_LEN) LOADK(k0 + 64);   // next K tile flies under compute

    f32x4 sc[4];
    __builtin_amdgcn_s_setprio(1);
    #pragma unroll
    for (int jt = 0; jt < 4; ++jt) {
      int row = (jt << 4) + l15, x = l15 & 7;
      bf16x8 b0 = *(const bf16x8*)&Kb[(row << 6) + (((quad    ) ^ x) << 3)];
      bf16x8 b1 = *(const bf16x8*)&Kb[(row << 6) + (((quad | 4) ^ x) << 3)];
      f32x4 acc = {0.f, 0.f, 0.f, 0.f};
      acc = __builtin_amdgcn_mfma_f32_16x16x32_bf16(aq0, b0, acc, 0, 0, 0);
      acc = __builtin_amdgcn_mfma_f32_16x16x32_bf16(aq1, b1, acc, 0, 0, 0);
      sc[jt] = acc;
    }
    __builtin_amdgcn_s_setprio(0);

    #pragma unroll
    for (int reg = 0; reg < 4; ++reg)
      #pragma unroll
      for (int jt = 0; jt < 4; ++jt) {
        float t = mvc[reg * 4 + jt] ? NEG_BIG : sc[jt][reg] * L2E_SC;
        lsum[reg] += __builtin_amdgcn_exp2f(t);
      }
    // mask for next tile: issued after last use, hides LLC latency
    if (k0 + 64 < S_LEN) LOADM(k0 + 64);
  }

  float invl[4];
  #pragma unroll
  for (int reg = 0; reg < 4; ++reg) {
    float t = lsum[reg];
    t += __shfl_xor(t, 1);
    t += __shfl_xor(t, 2);
    t += __shfl_xor(t, 4);
    t += __shfl_xor(t, 8);
    invl[reg] = 1.0f / t;
  }

  f32x4 cacc[4];
  #pragma unroll
  for (int jt = 0; jt < 4; ++jt) cacc[jt] = (f32x4){0.f, 0.f, 0.f, 0.f};

  LOADK(0);
  LOADV(0);
  LOADM(0);

  // ====================== pass 2: attn write + P·V MFMA ======================
  for (int k0 = 0; k0 < S_LEN; k0 += 64) {
    __syncthreads();          // prior compute done reading Kb/Vt
    STOREK();
    {
      float lo[8] = {pva.x, pva.y, pva.z, pva.w, pvb.x, pvb.y, pvb.z, pvb.w};
      float hi[8] = {pvc.x, pvc.y, pvc.z, pvc.w, pvd.x, pvd.y, pvd.z, pvd.w};
      int ch = vp >> 2, wi = (vp & 3) << 1;
      #pragma unroll
      for (int c = 0; c < 8; ++c) {
        int dd = vcb + c;
        *(unsigned int*)&Vt[(dd << 6) + ((ch ^ (dd & 7)) << 3) + wi] =
            packbf2(lo[c], hi[c]);
      }
    }
    __syncthreads();
    if (k0 + 64 < S_LEN) { LOADK(k0 + 64); LOADV(k0 + 64); }

    f32x4 sc[4];
    __builtin_amdgcn_s_setprio(1);
    #pragma unroll
    for (int jt = 0; jt < 4; ++jt) {
      int row = (jt << 4) + l15, x = l15 & 7;
      bf16x8 b0 = *(const bf16x8*)&Kb[(row << 6) + (((quad    ) ^ x) << 3)];
      bf16x8 b1 = *(const bf16x8*)&Kb[(row << 6) + (((quad | 4) ^ x) << 3)];
      f32x4 acc = {0.f, 0.f, 0.f, 0.f};
      acc = __builtin_amdgcn_mfma_f32_16x16x32_bf16(aq0, b0, acc, 0, 0, 0);
      acc = __builtin_amdgcn_mfma_f32_16x16x32_bf16(aq1, b1, acc, 0, 0, 0);
      sc[jt] = acc;
    }
    __builtin_amdgcn_s_setprio(0);

    #pragma unroll
    for (int reg = 0; reg < 4; ++reg) {
      float* prow = &Ps[(16 * w + 4 * quad + reg) * 68 + l15];
      float* arow = (float*)((char*)mrow[reg] + dAM);
      #pragma unroll
      for (int jt = 0; jt < 4; ++jt) {
        float t = mvc[reg * 4 + jt] ? NEG_BIG : sc[jt][reg] * L2E_SC;
        float p = __builtin_amdgcn_exp2f(t) * invl[reg];
        // write-once stream: nontemporal keeps K/V/mask resident in caches
        __builtin_nontemporal_store(p, &arow[k0 + (jt << 4)]);
        prow[jt << 4] = p;               // LDS, 2-way banks (free)
      }
    }
    // mask for next tile: issued after last use
    if (k0 + 64 < S_LEN) LOADM(k0 + 64);

    // P A-frags: wave reads only its own 16 rows (written by this wave above;
    // per-wave in-order LDS => no barrier needed)
    bf16x8 ap0, ap1;
    {
      const float* pp = &Ps[(16 * w + l15) * 68 + (quad << 3)];
      ap0 = pack8(((const float4*)pp)[0], ((const float4*)pp)[1]);
      ap1 = pack8(((const float4*)pp)[8], ((const float4*)pp)[9]);
    }
    __builtin_amdgcn_s_setprio(1);
    #pragma unroll
    for (int jt = 0; jt < 4; ++jt) {
      int d = (jt << 4) + l15, x = l15 & 7;
      bf16x8 bv0 = *(const bf16x8*)&Vt[(d << 6) + (((quad    ) ^ x) << 3)];
      bf16x8 bv1 = *(const bf16x8*)&Vt[(d << 6) + (((quad | 4) ^ x) << 3)];
      cacc[jt] = __builtin_amdgcn_mfma_f32_16x16x32_bf16(ap0, bv0, cacc[jt], 0, 0, 0);
      cacc[jt] = __builtin_amdgcn_mfma_f32_16x16x32_bf16(ap1, bv1, cacc[jt], 0, 0, 0);
    }
    __builtin_amdgcn_s_setprio(0);
  }

  // ---- ctx epilogue ----
  #pragma unroll
  for (int reg = 0; reg < 4; ++reg) {
    float* crow = ctxh + (size_t)(q0 + 16 * w + 4 * quad + reg) * DH + l15;
    #pragma unroll
    for (int jt = 0; jt < 4; ++jt)
      __builtin_nontemporal_store(cacc[jt][reg], &crow[jt << 4]);
  }
}

extern "C" void kernel_launch(void* const* d_in, const int* in_sizes, int n_in,
                              void* d_out, int out_size, void* d_ws, size_t ws_size,
                              hipStream_t stream) {
  (void)in_sizes; (void)n_in; (void)d_ws; (void)ws_size; (void)out_size;
  const float* Q = (const float*)d_in[0];
  const float* K = (const float*)d_in[1];
  const float* V = (const float*)d_in[2];
  const int*   M = (const int*)d_in[3];
  float* ctx  = (float*)d_out;
  float* attn = ctx + (size_t)NBATCH * NHEAD * S_LEN * DH;
  dim3 grid(S_LEN / 64, NHEAD, NBATCH);
  sdpa_mfma<<<grid, dim3(256), 0, stream>>>(Q, K, V, M, ctx, attn);
}